// Round 1
// baseline (945.837 us; speedup 1.0000x reference)
//
#include <hip/hip_runtime.h>

// Problem: out[b, i*32+j] = (data[b,:]·W1[:,i]) + (data[b,:]·W2[:,j])
//   data: [131072, 128] f32, W1/W2: [128, 32] f32, out: [131072, 1024] f32.
// HBM-write-bound: 512 MiB out + 64 MiB in => ~91 us floor at 6.3 TB/s.

#define BATCH_N   131072
#define D_FEAT    128
#define NBLOCKS   1024
#define TPB       256
#define RB        16              // rows per LDS batch

__global__ __launch_bounds__(TPB, 4)
void partition_kernel(const float* __restrict__ data,
                      const float* __restrict__ W1,
                      const float* __restrict__ W2,
                      float* __restrict__ out,
                      int rows_per_block) {
    // sX[r][0..31] = x1 values, sX[r][32..63] = x2 values, for RB rows.
    __shared__ __align__(16) float sX[RB][64];

    const int tid = threadIdx.x;
    const int c   = tid >> 2;     // 0..63: which output column (of the 64 dots)
    const int q   = tid & 3;      // 0..3 : which 32-wide quarter of D_FEAT

    // Per-thread weights: column c, elements d = q*32 .. q*32+31 (8 float4s).
    const float* __restrict__ W = (c < 32) ? W1 : W2;
    const int col = c & 31;
    float4 w[8];
#pragma unroll
    for (int k = 0; k < 8; ++k) {
        const int d = q * 32 + k * 4;
        w[k].x = W[(d + 0) * 32 + col];
        w[k].y = W[(d + 1) * 32 + col];
        w[k].z = W[(d + 2) * 32 + col];
        w[k].w = W[(d + 3) * 32 + col];
    }

    const int row0 = blockIdx.x * rows_per_block;
    const float4* __restrict__ data4 = (const float4*)data;  // 32 float4 / row
    float4* __restrict__ out4 = (float4*)out;                // 256 float4 / row

    const int i = tid >> 3;         // x1 index for write phase
    const int j = (tid * 4) & 31;   // x2 base index for write phase

    for (int rb = 0; rb < rows_per_block; rb += RB) {
        // ---- compute phase: fill sX for RB rows ----
        for (int r = 0; r < RB; ++r) {
            const int row = row0 + rb + r;
            const float4* dr = data4 + (size_t)row * 32 + q * 8;
            float acc = 0.f;
#pragma unroll
            for (int k = 0; k < 8; ++k) {
                const float4 v = dr[k];
                acc += w[k].x * v.x + w[k].y * v.y + w[k].z * v.z + w[k].w * v.w;
            }
            // butterfly across the 4 quarters (lanes differ in bits 0..1)
            acc += __shfl_xor(acc, 1);
            acc += __shfl_xor(acc, 2);
            if (q == 0) sX[r][c] = acc;
        }
        __syncthreads();

        // ---- write phase: 1 float4 store per thread per row ----
        for (int r = 0; r < RB; ++r) {
            const int row = row0 + rb + r;
            const float  x1 = sX[r][i];
            const float4 x2 = *(const float4*)&sX[r][32 + j];
            float4 o;
            o.x = x1 + x2.x;
            o.y = x1 + x2.y;
            o.z = x1 + x2.z;
            o.w = x1 + x2.w;
            out4[(size_t)row * 256 + tid] = o;
        }
        __syncthreads();   // sX reused next batch
    }
}

extern "C" void kernel_launch(void* const* d_in, const int* in_sizes, int n_in,
                              void* d_out, int out_size, void* d_ws, size_t ws_size,
                              hipStream_t stream) {
    const float* data = (const float*)d_in[0];
    const float* W1   = (const float*)d_in[1];
    const float* W2   = (const float*)d_in[2];
    float* out = (float*)d_out;

    const int rows_per_block = BATCH_N / NBLOCKS;  // 128
    partition_kernel<<<NBLOCKS, TPB, 0, stream>>>(data, W1, W2, out, rows_per_block);
}